// Round 7
// baseline (24.123 us; speedup 1.0000x reference)
//
#include <hip/hip_runtime.h>
#include <hip/hip_bf16.h>

#define NQ 6
#define DIM 64
#define NL 6

typedef _Float16 half8 __attribute__((ext_vector_type(8)));
typedef float f32x4 __attribute__((ext_vector_type(4)));

// ---------------------------------------------------------------------------
// Kernel 1 (v3): one WAVE per column of C; lane k holds amplitude k in 2
// VGPRs. Rotation gate = 2x shfl_xor + 8 FMA + 4 selects; fused CNOT-ring
// permutation = 2x shfl with per-lane src. Gate coefficients computed once
// by threads 0..35 into LDS (one barrier), read wave-uniformly.
// Output: u16[k*64+m] = Re(C[k][m]) f16, u16[4096 + k*64+m] = Im(C[k][m]).
// ---------------------------------------------------------------------------
__global__ __launch_bounds__(256) void build_C_kernel(const float* __restrict__ w,
                                                      unsigned short* __restrict__ Cu) {
    __shared__ __align__(16) float Uc[NL * NQ][8];
    const int tid  = threadIdx.x;
    const int lane = tid & 63;
    const int wave = tid >> 6;
    const int col  = blockIdx.x * 4 + wave;

    if (tid < NL * NQ) {
        float phi = w[3 * tid], th = w[3 * tid + 1], om = w[3 * tid + 2];
        float ch = cosf(0.5f * th), sh = sinf(0.5f * th);
        float ap = -0.5f * (phi + om), am = -0.5f * (phi - om);
        float epr = cosf(ap), epi = sinf(ap);
        float emr = cosf(am), emi = sinf(am);
        Uc[tid][0] =  epr * ch;  // u00r
        Uc[tid][1] =  epi * ch;  // u00i
        Uc[tid][2] = -emr * sh;  // u01r
        Uc[tid][3] =  emi * sh;  // u01i
        Uc[tid][4] =  emr * sh;  // u10r
        Uc[tid][5] =  emi * sh;  // u10i
        Uc[tid][6] =  epr * ch;  // u11r
        Uc[tid][7] = -epi * ch;  // u11i
    }
    __syncthreads();

    float re = (lane == col) ? 1.f : 0.f;
    float im = 0.f;

    #pragma unroll
    for (int l = 0; l < NL; ++l) {
        #pragma unroll
        for (int j = 0; j < NQ; ++j) {
            const int g = l * NQ + j;
            const int m = 1 << (5 - j);
            float4 uA = *(const float4*)&Uc[g][0];  // u00r u00i u01r u01i
            float4 uB = *(const float4*)&Uc[g][4];  // u10r u10i u11r u11i
            float pr = __shfl_xor(re, m);
            float pi = __shfl_xor(im, m);
            const bool hi = (lane & m) != 0;
            float Ar = hi ? uB.z : uA.x;
            float Ai = hi ? uB.w : uA.y;
            float Br = hi ? uB.x : uA.z;
            float Bi = hi ? uB.y : uA.w;
            float nr = Ar * re - Ai * im + Br * pr - Bi * pi;
            float ni = Ar * im + Ai * re + Br * pi + Bi * pr;
            re = nr; im = ni;
        }
        // fused CNOT-ring permutation: new[k] = old[src(k)]
        const int r = l % (NQ - 1) + 1;
        int src = lane;
        #pragma unroll
        for (int jj = NQ - 1; jj >= 0; --jj) {
            int cm = 1 << (5 - jj);
            int tm = 1 << (5 - ((jj + r) % NQ));
            src = (src & cm) ? (src ^ tm) : src;
        }
        re = __shfl(re, src);
        im = __shfl(im, src);
    }

    _Float16 hr = (_Float16)re, hi16 = (_Float16)im;
    Cu[lane * 64 + col]        = __builtin_bit_cast(unsigned short, hr);
    Cu[4096 + lane * 64 + col] = __builtin_bit_cast(unsigned short, hi16);
}

// ---------------------------------------------------------------------------
// Kernel 2 (v4): NO LDS, NO barriers. B-fragments built in registers.
// k-map: f16 elem k = s*32 + g*8 + e  ->  psi[k] = F(s,g) * G(e) where
// F = (s?sn0:cs0)(g&2?sn1:cs2... qubits 1,2 by g bits) and G(e) = products
// of qubits 3,4,5 by e bits (matches the verified packed layout).
// Lane (g,n) in grp-iteration handles sample sbase+grp*16+n: computes its
// own 6 sincos (4x redundant across g — cheap) and packs B0/B1 directly.
// t-outer MFMA loop keeps only 8 acc VGPRs live; launch_bounds(256,4)
// pins VGPR <= 128 -> 4 waves/SIMD. Epilogue/signs/stores = round 6.
// ---------------------------------------------------------------------------
__global__ __launch_bounds__(256, 4) void qexp_mfma(const float* __restrict__ x,
                                                    const unsigned* __restrict__ C,
                                                    float* __restrict__ out,
                                                    int batch) {
    const int tid  = threadIdx.x;
    const int lane = tid & 63;
    const int wave = tid >> 6;
    const int n    = lane & 15;
    const int g    = lane >> 4;
    const int sbase = blockIdx.x * 256 + wave * 64;

    // ---- persistent A-frags: C matrix, 16 frags (4 ktiles x 2 ksteps x Re/Im)
    half8 Ar[4][2], Ai[4][2];
    #pragma unroll
    for (int t = 0; t < 4; ++t)
        #pragma unroll
        for (int s = 0; s < 2; ++s) {
            int dw = (t * 16 + n) * 32 + s * 16 + g * 4;
            Ar[t][s] = __builtin_bit_cast(half8, *(const int4*)(C + dw));
            Ai[t][s] = __builtin_bit_cast(half8, *(const int4*)(C + 2048 + dw));
        }

    const unsigned m2 = (unsigned)(g >> 1) << 31;   // k_out bit3 sign (j=2)
    const unsigned m3 = (unsigned)(g & 1) << 31;    // k_out bit2 sign (j=3)

    #pragma unroll 1
    for (int grp = 0; grp < 4; ++grp) {
        const int sample = sbase + grp * 16 + n;

        // ---- per-lane trig for this grp's sample
        const float2* xp = (const float2*)(x + (size_t)sample * NQ);
        float2 x01 = xp[0], x23 = xp[1], x45 = xp[2];
        float xa[6] = {x01.x, x01.y, x23.x, x23.y, x45.x, x45.y};
        float cs[6], sn[6];
        #pragma unroll
        for (int j = 0; j < 6; ++j) {
            float a = 1.57079632679489662f * xa[j];
            __sincosf(a, &sn[j], &cs[j]);
        }

        // ---- G(e): qubits 3,4,5 selected by e bits (b2=q3, b1=q4, b0=q5)
        float b00 = cs[3] * cs[4], b01 = cs[3] * sn[4];
        float b10 = sn[3] * cs[4], b11 = sn[3] * sn[4];
        float lo[8] = {b00 * cs[5], b00 * sn[5], b01 * cs[5], b01 * sn[5],
                       b10 * cs[5], b10 * sn[5], b11 * cs[5], b11 * sn[5]};
        // ---- F(s,g): qubit0 <- s, qubit1 <- g bit1, qubit2 <- g bit0
        float fg = ((g & 2) ? sn[1] : cs[1]) * ((g & 1) ? sn[2] : cs[2]);
        float F0 = cs[0] * fg, F1 = sn[0] * fg;

        int4 B0d, B1d;
        B0d.x = __builtin_bit_cast(int, __builtin_amdgcn_cvt_pkrtz(F0 * lo[0], F0 * lo[1]));
        B0d.y = __builtin_bit_cast(int, __builtin_amdgcn_cvt_pkrtz(F0 * lo[2], F0 * lo[3]));
        B0d.z = __builtin_bit_cast(int, __builtin_amdgcn_cvt_pkrtz(F0 * lo[4], F0 * lo[5]));
        B0d.w = __builtin_bit_cast(int, __builtin_amdgcn_cvt_pkrtz(F0 * lo[6], F0 * lo[7]));
        B1d.x = __builtin_bit_cast(int, __builtin_amdgcn_cvt_pkrtz(F1 * lo[0], F1 * lo[1]));
        B1d.y = __builtin_bit_cast(int, __builtin_amdgcn_cvt_pkrtz(F1 * lo[2], F1 * lo[3]));
        B1d.z = __builtin_bit_cast(int, __builtin_amdgcn_cvt_pkrtz(F1 * lo[4], F1 * lo[5]));
        B1d.w = __builtin_bit_cast(int, __builtin_amdgcn_cvt_pkrtz(F1 * lo[6], F1 * lo[7]));
        half8 B0 = __builtin_bit_cast(half8, B0d);
        half8 B1 = __builtin_bit_cast(half8, B1d);

        // ---- MFMA: t-outer so only one t's acc (8 VGPR) is live at a time
        float s01[4], s23[4], a02[4], T[4];
        #pragma unroll
        for (int t = 0; t < 4; ++t) {
            f32x4 ar = (f32x4)0.f, ai = (f32x4)0.f;
            ar = __builtin_amdgcn_mfma_f32_16x16x32_f16(Ar[t][0], B0, ar, 0, 0, 0);
            ar = __builtin_amdgcn_mfma_f32_16x16x32_f16(Ar[t][1], B1, ar, 0, 0, 0);
            ai = __builtin_amdgcn_mfma_f32_16x16x32_f16(Ai[t][0], B0, ai, 0, 0, 0);
            ai = __builtin_amdgcn_mfma_f32_16x16x32_f16(Ai[t][1], B1, ai, 0, 0, 0);
            float p0 = fmaf(ar[0], ar[0], ai[0] * ai[0]);
            float p1 = fmaf(ar[1], ar[1], ai[1] * ai[1]);
            float p2 = fmaf(ar[2], ar[2], ai[2] * ai[2]);
            float p3 = fmaf(ar[3], ar[3], ai[3] * ai[3]);
            s01[t] = p0 + p1;
            s23[t] = p2 + p3;
            a02[t] = p0 + p2;
            T[t]   = s01[t] + s23[t];
        }

        // factored sign-sums: k_out = t*16 + g*4 + i
        float u = T[0] + T[1], v = T[2] + T[3];
        float P = u + v;
        float o0 = u - v;                      // j=0: sign = bit5 = t&2
        float w2 = T[0] + T[2];
        float o1 = fmaf(2.f, w2, -P);          // j=1: sign = bit4 = t&1
        float S01 = (s01[0] + s01[1]) + (s01[2] + s01[3]);
        float o4 = fmaf(2.f, S01, -P);         // j=4: sign = bit1 = i&2
        float Sa = (a02[0] + a02[1]) + (a02[2] + a02[3]);
        float o5 = fmaf(2.f, Sa, -P);          // j=5: sign = bit0 = i&1
        float o2 = __builtin_bit_cast(float, __builtin_bit_cast(unsigned, P) ^ m2);
        float o3 = __builtin_bit_cast(float, __builtin_bit_cast(unsigned, P) ^ m3);

        // fold the 4 k-groups (lanes n, n+16, n+32, n+48)
        o0 += __shfl_xor(o0, 16); o0 += __shfl_xor(o0, 32);
        o1 += __shfl_xor(o1, 16); o1 += __shfl_xor(o1, 32);
        o2 += __shfl_xor(o2, 16); o2 += __shfl_xor(o2, 32);
        o3 += __shfl_xor(o3, 16); o3 += __shfl_xor(o3, 32);
        o4 += __shfl_xor(o4, 16); o4 += __shfl_xor(o4, 32);
        o5 += __shfl_xor(o5, 16); o5 += __shfl_xor(o5, 32);

        float2* op = (float2*)(out + (size_t)sample * 6);
        if (g == 0)      { op[0] = make_float2(o0, o1); op[1] = make_float2(o2, o3); }
        else if (g == 1) { op[2] = make_float2(o4, o5); }
    }
}

extern "C" void kernel_launch(void* const* d_in, const int* in_sizes, int n_in,
                              void* d_out, int out_size, void* d_ws, size_t ws_size,
                              hipStream_t stream) {
    const float* x = (const float*)d_in[0];
    const float* w = (const float*)d_in[1];
    unsigned* C = (unsigned*)d_ws;   // 4096 dwords = 16 KB (f16-packed Re|Im)
    float* out = (float*)d_out;
    const int batch = in_sizes[0] / NQ;

    build_C_kernel<<<16, 256, 0, stream>>>(w, (unsigned short*)C);
    const int blocks = (batch + 255) / 256;   // 1024 blocks x 256 threads
    qexp_mfma<<<blocks, 256, 0, stream>>>(x, C, out, batch);
}

// Round 8
// 20.962 us; speedup vs baseline: 1.1508x; 1.1508x over previous
//
#include <hip/hip_runtime.h>
#include <hip/hip_bf16.h>

#define NQ 6
#define DIM 64
#define NL 6

typedef _Float16 half8 __attribute__((ext_vector_type(8)));
typedef float f32x4 __attribute__((ext_vector_type(4)));

// ---------------------------------------------------------------------------
// Kernel 1 (v3): one WAVE per column of C; lane k holds amplitude k in 2
// VGPRs. Rotation gate = 2x shfl_xor + 8 FMA + 4 selects; fused CNOT-ring
// permutation = 2x shfl with per-lane src. Gate coefficients computed once
// by threads 0..35 into LDS (one barrier), read wave-uniformly.
// Output: u16[k*64+m] = Re(C[k][m]) f16, u16[4096 + k*64+m] = Im(C[k][m]).
// ---------------------------------------------------------------------------
__global__ __launch_bounds__(256) void build_C_kernel(const float* __restrict__ w,
                                                      unsigned short* __restrict__ Cu) {
    __shared__ __align__(16) float Uc[NL * NQ][8];
    const int tid  = threadIdx.x;
    const int lane = tid & 63;
    const int wave = tid >> 6;
    const int col  = blockIdx.x * 4 + wave;

    if (tid < NL * NQ) {
        float phi = w[3 * tid], th = w[3 * tid + 1], om = w[3 * tid + 2];
        float ch = cosf(0.5f * th), sh = sinf(0.5f * th);
        float ap = -0.5f * (phi + om), am = -0.5f * (phi - om);
        float epr = cosf(ap), epi = sinf(ap);
        float emr = cosf(am), emi = sinf(am);
        Uc[tid][0] =  epr * ch;  // u00r
        Uc[tid][1] =  epi * ch;  // u00i
        Uc[tid][2] = -emr * sh;  // u01r
        Uc[tid][3] =  emi * sh;  // u01i
        Uc[tid][4] =  emr * sh;  // u10r
        Uc[tid][5] =  emi * sh;  // u10i
        Uc[tid][6] =  epr * ch;  // u11r
        Uc[tid][7] = -epi * ch;  // u11i
    }
    __syncthreads();

    float re = (lane == col) ? 1.f : 0.f;
    float im = 0.f;

    #pragma unroll
    for (int l = 0; l < NL; ++l) {
        #pragma unroll
        for (int j = 0; j < NQ; ++j) {
            const int g = l * NQ + j;
            const int m = 1 << (5 - j);
            float4 uA = *(const float4*)&Uc[g][0];  // u00r u00i u01r u01i
            float4 uB = *(const float4*)&Uc[g][4];  // u10r u10i u11r u11i
            float pr = __shfl_xor(re, m);
            float pi = __shfl_xor(im, m);
            const bool hi = (lane & m) != 0;
            float Ar = hi ? uB.z : uA.x;
            float Ai = hi ? uB.w : uA.y;
            float Br = hi ? uB.x : uA.z;
            float Bi = hi ? uB.y : uA.w;
            float nr = Ar * re - Ai * im + Br * pr - Bi * pi;
            float ni = Ar * im + Ai * re + Br * pi + Bi * pr;
            re = nr; im = ni;
        }
        // fused CNOT-ring permutation: new[k] = old[src(k)]
        const int r = l % (NQ - 1) + 1;
        int src = lane;
        #pragma unroll
        for (int jj = NQ - 1; jj >= 0; --jj) {
            int cm = 1 << (5 - jj);
            int tm = 1 << (5 - ((jj + r) % NQ));
            src = (src & cm) ? (src ^ tm) : src;
        }
        re = __shfl(re, src);
        im = __shfl(im, src);
    }

    _Float16 hr = (_Float16)re, hi16 = (_Float16)im;
    Cu[lane * 64 + col]        = __builtin_bit_cast(unsigned short, hr);
    Cu[4096 + lane * 64 + col] = __builtin_bit_cast(unsigned short, hi16);
}

// ---------------------------------------------------------------------------
// Kernel 2 (round-6 structure + (256,4) register cap).
// Per wave: 64 samples. psi (f16) per lane -> LDS (stride 36 dwords).
// grp loop ROLLED so only one grp's acc (32 VGPR) is live; launch_bounds
// (256,4) caps VGPR at 128 -> 4 blocks/CU resident (occupancy theory).
// Epilogue: factored sign-sums (round 6, verified).
// ---------------------------------------------------------------------------
__global__ __launch_bounds__(256, 4) void qexp_mfma(const float* __restrict__ x,
                                                    const unsigned* __restrict__ C,
                                                    float* __restrict__ out,
                                                    int batch) {
    __shared__ __align__(16) unsigned Psi[256 * 36];  // 36 KB, 144 B/row
    const int tid  = threadIdx.x;
    const int lane = tid & 63;
    const int wave = tid >> 6;
    const int n    = lane & 15;
    const int g    = lane >> 4;
    const int sbase = blockIdx.x * 256 + wave * 64;

    // ---- persistent A-frags: C matrix, 16 frags (4 ktiles x 2 ksteps x Re/Im)
    half8 Ar[4][2], Ai[4][2];
    #pragma unroll
    for (int t = 0; t < 4; ++t)
        #pragma unroll
        for (int s = 0; s < 2; ++s) {
            int dw = (t * 16 + n) * 32 + s * 16 + g * 4;
            Ar[t][s] = __builtin_bit_cast(half8, *(const int4*)(C + dw));
            Ai[t][s] = __builtin_bit_cast(half8, *(const int4*)(C + 2048 + dw));
        }

    // ---- psi for sample sbase+lane, f16-packed into LDS row tid
    {
        const float2* xp = (const float2*)(x + (size_t)(sbase + lane) * NQ);
        float2 x01 = xp[0], x23 = xp[1], x45 = xp[2];
        float xa[6] = {x01.x, x01.y, x23.x, x23.y, x45.x, x45.y};
        float cs[6], sn[6];
        #pragma unroll
        for (int j = 0; j < 6; ++j) {
            float a = 1.57079632679489662f * xa[j];
            __sincosf(a, &sn[j], &cs[j]);
        }
        float a00 = cs[0] * cs[1], a01 = cs[0] * sn[1];
        float a10 = sn[0] * cs[1], a11 = sn[0] * sn[1];
        float hi[8] = {a00 * cs[2], a00 * sn[2], a01 * cs[2], a01 * sn[2],
                       a10 * cs[2], a10 * sn[2], a11 * cs[2], a11 * sn[2]};
        float b00 = cs[3] * cs[4], b01 = cs[3] * sn[4];
        float b10 = sn[3] * cs[4], b11 = sn[3] * sn[4];
        float lo[8] = {b00 * cs[5], b00 * sn[5], b01 * cs[5], b01 * sn[5],
                       b10 * cs[5], b10 * sn[5], b11 * cs[5], b11 * sn[5]};
        const int rowbase = tid * 36;
        #pragma unroll
        for (int c = 0; c < 8; ++c) {
            float h = hi[c];
            int4 d;
            d.x = __builtin_bit_cast(int, __builtin_amdgcn_cvt_pkrtz(h * lo[0], h * lo[1]));
            d.y = __builtin_bit_cast(int, __builtin_amdgcn_cvt_pkrtz(h * lo[2], h * lo[3]));
            d.z = __builtin_bit_cast(int, __builtin_amdgcn_cvt_pkrtz(h * lo[4], h * lo[5]));
            d.w = __builtin_bit_cast(int, __builtin_amdgcn_cvt_pkrtz(h * lo[6], h * lo[7]));
            *(int4*)(&Psi[rowbase + c * 4]) = d;
        }
    }
    __syncthreads();

    const unsigned m2 = (unsigned)(g >> 1) << 31;   // k_out bit3 sign (j=2)
    const unsigned m3 = (unsigned)(g & 1) << 31;    // k_out bit2 sign (j=3)

    #pragma unroll 1
    for (int grp = 0; grp < 4; ++grp) {
        f32x4 accr[4], acci[4];
        #pragma unroll
        for (int t = 0; t < 4; ++t) { accr[t] = (f32x4)0.f; acci[t] = (f32x4)0.f; }

        #pragma unroll
        for (int s = 0; s < 2; ++s) {
            int bd = (wave * 64 + grp * 16 + n) * 36 + s * 16 + g * 4;
            half8 B = __builtin_bit_cast(half8, *(const int4*)(&Psi[bd]));
            #pragma unroll
            for (int t = 0; t < 4; ++t) {
                accr[t] = __builtin_amdgcn_mfma_f32_16x16x32_f16(Ar[t][s], B, accr[t], 0, 0, 0);
                acci[t] = __builtin_amdgcn_mfma_f32_16x16x32_f16(Ai[t][s], B, acci[t], 0, 0, 0);
            }
        }

        // factored sign-sums: k_out = t*16 + g*4 + i
        float s01[4], s23[4], a02[4], T[4];
        #pragma unroll
        for (int t = 0; t < 4; ++t) {
            float p0 = fmaf(accr[t][0], accr[t][0], acci[t][0] * acci[t][0]);
            float p1 = fmaf(accr[t][1], accr[t][1], acci[t][1] * acci[t][1]);
            float p2 = fmaf(accr[t][2], accr[t][2], acci[t][2] * acci[t][2]);
            float p3 = fmaf(accr[t][3], accr[t][3], acci[t][3] * acci[t][3]);
            s01[t] = p0 + p1;
            s23[t] = p2 + p3;
            a02[t] = p0 + p2;
            T[t]   = s01[t] + s23[t];
        }
        float u = T[0] + T[1], v = T[2] + T[3];
        float P = u + v;
        float o0 = u - v;                      // j=0: sign = bit5 = t&2
        float w2 = T[0] + T[2];
        float o1 = fmaf(2.f, w2, -P);          // j=1: sign = bit4 = t&1
        float S01 = (s01[0] + s01[1]) + (s01[2] + s01[3]);
        float o4 = fmaf(2.f, S01, -P);         // j=4: sign = bit1 = i&2
        float Sa = (a02[0] + a02[1]) + (a02[2] + a02[3]);
        float o5 = fmaf(2.f, Sa, -P);          // j=5: sign = bit0 = i&1
        float o2 = __builtin_bit_cast(float, __builtin_bit_cast(unsigned, P) ^ m2);
        float o3 = __builtin_bit_cast(float, __builtin_bit_cast(unsigned, P) ^ m3);

        // fold the 4 k-groups (lanes n, n+16, n+32, n+48)
        o0 += __shfl_xor(o0, 16); o0 += __shfl_xor(o0, 32);
        o1 += __shfl_xor(o1, 16); o1 += __shfl_xor(o1, 32);
        o2 += __shfl_xor(o2, 16); o2 += __shfl_xor(o2, 32);
        o3 += __shfl_xor(o3, 16); o3 += __shfl_xor(o3, 32);
        o4 += __shfl_xor(o4, 16); o4 += __shfl_xor(o4, 32);
        o5 += __shfl_xor(o5, 16); o5 += __shfl_xor(o5, 32);

        int sample = sbase + grp * 16 + n;
        float2* op = (float2*)(out + (size_t)sample * 6);
        if (g == 0)      { op[0] = make_float2(o0, o1); op[1] = make_float2(o2, o3); }
        else if (g == 1) { op[2] = make_float2(o4, o5); }
    }
}

extern "C" void kernel_launch(void* const* d_in, const int* in_sizes, int n_in,
                              void* d_out, int out_size, void* d_ws, size_t ws_size,
                              hipStream_t stream) {
    const float* x = (const float*)d_in[0];
    const float* w = (const float*)d_in[1];
    unsigned* C = (unsigned*)d_ws;   // 4096 dwords = 16 KB (f16-packed Re|Im)
    float* out = (float*)d_out;
    const int batch = in_sizes[0] / NQ;

    build_C_kernel<<<16, 256, 0, stream>>>(w, (unsigned short*)C);
    const int blocks = (batch + 255) / 256;   // 1024 blocks x 256 threads
    qexp_mfma<<<blocks, 256, 0, stream>>>(x, C, out, batch);
}

// Round 10
// 17.727 us; speedup vs baseline: 1.3608x; 1.1825x over previous
//
#include <hip/hip_runtime.h>
#include <hip/hip_bf16.h>

#define NQ 6
#define DIM 64
#define NL 6

typedef _Float16 half8 __attribute__((ext_vector_type(8)));
typedef float f32x4 __attribute__((ext_vector_type(4)));

// ---------------------------------------------------------------------------
// Kernel 1 (v4): one WAVE per column; lane k holds amplitude k. Gate chain
// as round 8 (verified). Output written pre-permuted in MFMA FRAG ORDER:
//   halfword idx (ri,t,s,lane,d,h) = ri*4096 + (((t*2+s)*64 + lane)*4 + d)*2 + h
// where frag element (t,s,lane=(g,n),d,h) = C[row=t*16+n][kin=s*32+g*8+2d+h].
// This wave computes column kin=col: s=col>>5, g=(col>>3)&3, e=col&7=2d+h;
// lane `row` scatters its (re,im) to (t=row>>4, destLane=g*16+(row&15)).
// qexp then loads A-frags fully coalesced (64 lanes x 16B contiguous).
// ---------------------------------------------------------------------------
__global__ __launch_bounds__(256) void build_C_kernel(const float* __restrict__ w,
                                                      unsigned short* __restrict__ Cu) {
    __shared__ __align__(16) float Uc[NL * NQ][8];
    const int tid  = threadIdx.x;
    const int lane = tid & 63;
    const int wave = tid >> 6;
    const int col  = blockIdx.x * 4 + wave;

    if (tid < NL * NQ) {
        float phi = w[3 * tid], th = w[3 * tid + 1], om = w[3 * tid + 2];
        float ch = cosf(0.5f * th), sh = sinf(0.5f * th);
        float ap = -0.5f * (phi + om), am = -0.5f * (phi - om);
        float epr = cosf(ap), epi = sinf(ap);
        float emr = cosf(am), emi = sinf(am);
        Uc[tid][0] =  epr * ch;  // u00r
        Uc[tid][1] =  epi * ch;  // u00i
        Uc[tid][2] = -emr * sh;  // u01r
        Uc[tid][3] =  emi * sh;  // u01i
        Uc[tid][4] =  emr * sh;  // u10r
        Uc[tid][5] =  emi * sh;  // u10i
        Uc[tid][6] =  epr * ch;  // u11r
        Uc[tid][7] = -epi * ch;  // u11i
    }
    __syncthreads();

    float re = (lane == col) ? 1.f : 0.f;
    float im = 0.f;

    #pragma unroll
    for (int l = 0; l < NL; ++l) {
        #pragma unroll
        for (int j = 0; j < NQ; ++j) {
            const int g = l * NQ + j;
            const int m = 1 << (5 - j);
            float4 uA = *(const float4*)&Uc[g][0];  // u00r u00i u01r u01i
            float4 uB = *(const float4*)&Uc[g][4];  // u10r u10i u11r u11i
            float pr = __shfl_xor(re, m);
            float pi = __shfl_xor(im, m);
            const bool hi = (lane & m) != 0;
            float Ar = hi ? uB.z : uA.x;
            float Ai = hi ? uB.w : uA.y;
            float Br = hi ? uB.x : uA.z;
            float Bi = hi ? uB.y : uA.w;
            float nr = Ar * re - Ai * im + Br * pr - Bi * pi;
            float ni = Ar * im + Ai * re + Br * pi + Bi * pr;
            re = nr; im = ni;
        }
        // fused CNOT-ring permutation: new[k] = old[src(k)]
        const int r = l % (NQ - 1) + 1;
        int src = lane;
        #pragma unroll
        for (int jj = NQ - 1; jj >= 0; --jj) {
            int cm = 1 << (5 - jj);
            int tm = 1 << (5 - ((jj + r) % NQ));
            src = (src & cm) ? (src ^ tm) : src;
        }
        re = __shfl(re, src);
        im = __shfl(im, src);
    }

    // scatter into frag order (one-time 16 KB)
    _Float16 hr = (_Float16)re, hi16 = (_Float16)im;
    const int s  = col >> 5;
    const int g2 = (col >> 3) & 3;
    const int e  = col & 7;
    const int t  = lane >> 4;
    const int n  = lane & 15;
    const int dl = g2 * 16 + n;
    const int base = (((t * 2 + s) * 64 + dl) * 4 + (e >> 1)) * 2 + (e & 1);
    Cu[base]        = __builtin_bit_cast(unsigned short, hr);
    Cu[4096 + base] = __builtin_bit_cast(unsigned short, hi16);
}

// ---------------------------------------------------------------------------
// Kernel 2 (round-8 arithmetic, frag-ordered A-loads).
// A-frag load: dwordx4 at ((t*2+s)*64 + lane)*4 — 64 lanes x 16B contiguous
// per instruction, identical across waves (L1 broadcast). Everything else
// (psi->LDS staging, rolled grp loop, factored sign epilogue) = round 8.
// ---------------------------------------------------------------------------
__global__ __launch_bounds__(256, 4) void qexp_mfma(const float* __restrict__ x,
                                                    const unsigned* __restrict__ C,
                                                    float* __restrict__ out,
                                                    int batch) {
    __shared__ __align__(16) unsigned Psi[256 * 36];  // 36 KB, 144 B/row
    const int tid  = threadIdx.x;
    const int lane = tid & 63;
    const int wave = tid >> 6;
    const int n    = lane & 15;
    const int g    = lane >> 4;
    const int sbase = blockIdx.x * 256 + wave * 64;

    // ---- persistent A-frags: coalesced frag-ordered loads
    half8 Ar[4][2], Ai[4][2];
    #pragma unroll
    for (int t = 0; t < 4; ++t)
        #pragma unroll
        for (int s = 0; s < 2; ++s) {
            int dw = ((t * 2 + s) * 64 + lane) * 4;
            Ar[t][s] = __builtin_bit_cast(half8, *(const int4*)(C + dw));
            Ai[t][s] = __builtin_bit_cast(half8, *(const int4*)(C + 2048 + dw));
        }

    // ---- psi for sample sbase+lane, f16-packed into LDS row tid
    {
        const float2* xp = (const float2*)(x + (size_t)(sbase + lane) * NQ);
        float2 x01 = xp[0], x23 = xp[1], x45 = xp[2];
        float xa[6] = {x01.x, x01.y, x23.x, x23.y, x45.x, x45.y};
        float cs[6], sn[6];
        #pragma unroll
        for (int j = 0; j < 6; ++j) {
            float a = 1.57079632679489662f * xa[j];
            __sincosf(a, &sn[j], &cs[j]);
        }
        float a00 = cs[0] * cs[1], a01 = cs[0] * sn[1];
        float a10 = sn[0] * cs[1], a11 = sn[0] * sn[1];
        float hi[8] = {a00 * cs[2], a00 * sn[2], a01 * cs[2], a01 * sn[2],
                       a10 * cs[2], a10 * sn[2], a11 * cs[2], a11 * sn[2]};
        float b00 = cs[3] * cs[4], b01 = cs[3] * sn[4];
        float b10 = sn[3] * cs[4], b11 = sn[3] * sn[4];
        float lo[8] = {b00 * cs[5], b00 * sn[5], b01 * cs[5], b01 * sn[5],
                       b10 * cs[5], b10 * sn[5], b11 * cs[5], b11 * sn[5]};
        const int rowbase = tid * 36;
        #pragma unroll
        for (int c = 0; c < 8; ++c) {
            float h = hi[c];
            int4 d;
            d.x = __builtin_bit_cast(int, __builtin_amdgcn_cvt_pkrtz(h * lo[0], h * lo[1]));
            d.y = __builtin_bit_cast(int, __builtin_amdgcn_cvt_pkrtz(h * lo[2], h * lo[3]));
            d.z = __builtin_bit_cast(int, __builtin_amdgcn_cvt_pkrtz(h * lo[4], h * lo[5]));
            d.w = __builtin_bit_cast(int, __builtin_amdgcn_cvt_pkrtz(h * lo[6], h * lo[7]));
            *(int4*)(&Psi[rowbase + c * 4]) = d;
        }
    }
    __syncthreads();

    const unsigned m2 = (unsigned)(g >> 1) << 31;   // k_out bit3 sign (j=2)
    const unsigned m3 = (unsigned)(g & 1) << 31;    // k_out bit2 sign (j=3)

    #pragma unroll 1
    for (int grp = 0; grp < 4; ++grp) {
        f32x4 accr[4], acci[4];
        #pragma unroll
        for (int t = 0; t < 4; ++t) { accr[t] = (f32x4)0.f; acci[t] = (f32x4)0.f; }

        #pragma unroll
        for (int s = 0; s < 2; ++s) {
            int bd = (wave * 64 + grp * 16 + n) * 36 + s * 16 + g * 4;
            half8 B = __builtin_bit_cast(half8, *(const int4*)(&Psi[bd]));
            #pragma unroll
            for (int t = 0; t < 4; ++t) {
                accr[t] = __builtin_amdgcn_mfma_f32_16x16x32_f16(Ar[t][s], B, accr[t], 0, 0, 0);
                acci[t] = __builtin_amdgcn_mfma_f32_16x16x32_f16(Ai[t][s], B, acci[t], 0, 0, 0);
            }
        }

        // factored sign-sums: k_out = t*16 + g*4 + i
        float s01[4], s23[4], a02[4], T[4];
        #pragma unroll
        for (int t = 0; t < 4; ++t) {
            float p0 = fmaf(accr[t][0], accr[t][0], acci[t][0] * acci[t][0]);
            float p1 = fmaf(accr[t][1], accr[t][1], acci[t][1] * acci[t][1]);
            float p2 = fmaf(accr[t][2], accr[t][2], acci[t][2] * acci[t][2]);
            float p3 = fmaf(accr[t][3], accr[t][3], acci[t][3] * acci[t][3]);
            s01[t] = p0 + p1;
            s23[t] = p2 + p3;
            a02[t] = p0 + p2;
            T[t]   = s01[t] + s23[t];
        }
        float u = T[0] + T[1], v = T[2] + T[3];
        float P = u + v;
        float o0 = u - v;                      // j=0: sign = bit5 = t&2
        float w2 = T[0] + T[2];
        float o1 = fmaf(2.f, w2, -P);          // j=1: sign = bit4 = t&1
        float S01 = (s01[0] + s01[1]) + (s01[2] + s01[3]);
        float o4 = fmaf(2.f, S01, -P);         // j=4: sign = bit1 = i&2
        float Sa = (a02[0] + a02[1]) + (a02[2] + a02[3]);
        float o5 = fmaf(2.f, Sa, -P);          // j=5: sign = bit0 = i&1
        float o2 = __builtin_bit_cast(float, __builtin_bit_cast(unsigned, P) ^ m2);
        float o3 = __builtin_bit_cast(float, __builtin_bit_cast(unsigned, P) ^ m3);

        // fold the 4 k-groups (lanes n, n+16, n+32, n+48)
        o0 += __shfl_xor(o0, 16); o0 += __shfl_xor(o0, 32);
        o1 += __shfl_xor(o1, 16); o1 += __shfl_xor(o1, 32);
        o2 += __shfl_xor(o2, 16); o2 += __shfl_xor(o2, 32);
        o3 += __shfl_xor(o3, 16); o3 += __shfl_xor(o3, 32);
        o4 += __shfl_xor(o4, 16); o4 += __shfl_xor(o4, 32);
        o5 += __shfl_xor(o5, 16); o5 += __shfl_xor(o5, 32);

        int sample = sbase + grp * 16 + n;
        float2* op = (float2*)(out + (size_t)sample * 6);
        if (g == 0)      { op[0] = make_float2(o0, o1); op[1] = make_float2(o2, o3); }
        else if (g == 1) { op[2] = make_float2(o4, o5); }
    }
}

extern "C" void kernel_launch(void* const* d_in, const int* in_sizes, int n_in,
                              void* d_out, int out_size, void* d_ws, size_t ws_size,
                              hipStream_t stream) {
    const float* x = (const float*)d_in[0];
    const float* w = (const float*)d_in[1];
    unsigned* C = (unsigned*)d_ws;   // 4096 dwords = 16 KB (frag-ordered Re|Im)
    float* out = (float*)d_out;
    const int batch = in_sizes[0] / NQ;

    build_C_kernel<<<16, 256, 0, stream>>>(w, (unsigned short*)C);
    const int blocks = (batch + 255) / 256;   // 1024 blocks x 256 threads
    qexp_mfma<<<blocks, 256, 0, stream>>>(x, C, out, batch);
}